// Round 3
// baseline (117.915 us; speedup 1.0000x reference)
//
#include <hip/hip_runtime.h>
#include <hip/hip_bf16.h>

#define NN 16384
#define DD 64
#define TT 128                 // 128-row tiles: NN/128
#define NTRI ((TT*(TT+1))/2)   // 8256 triangular tile-pairs
#define NBLK 2048              // persistent blocks: 8/CU -> 100% occupancy
#define NPOSB (NN/4)           // norm blocks (4 rows each)
#define SCREEN_T 0.49f         // conservative: hinge>0 needs gram > ~0.5-3e-5

constexpr float F_EPS_PD   = 1e-6f;
constexpr float F_EPS_NORM = 1e-6f;

using bf16x8 = __attribute__((ext_vector_type(8))) short;
using f32x4  = __attribute__((ext_vector_type(4))) float;

__device__ __forceinline__ float wave_sum_f(float v) {
    #pragma unroll
    for (int o = 32; o >= 1; o >>= 1) v += __shfl_xor(v, o);
    return v;
}

__device__ __forceinline__ int tri_off(int t) { return t * TT - (t * (t - 1)) / 2; }

// ---------------------------------------------------------------------------
// Kernel 1: per-row normalize + bf16 copy + u/vc terms + exact fp32 pos loss.
//   u[i]  = sq_i + 2*eps*s_i
//   vc[j] = sq_j - 2*eps*s_j + D*eps*eps      (d2 = u_i + vc_j - 2*gram)
// ---------------------------------------------------------------------------
__global__ __launch_bounds__(256) void norm_kernel(
    const float* __restrict__ emb, const int* __restrict__ pidx,
    float* __restrict__ u, float* __restrict__ vc,
    __hip_bfloat16* __restrict__ ebf, float* __restrict__ posP) {
    int w    = threadIdx.x >> 6;
    int row  = blockIdx.x * 4 + w;
    int lane = threadIdx.x & 63;
    int j    = pidx[row];
    float x  = emb[(size_t)row * DD + lane];
    float xj = emb[(size_t)j   * DD + lane];

    float n2  = wave_sum_f(x * x);
    float sx  = wave_sum_f(x);
    float n2j = wave_sum_f(xj * xj);
    float sxj = wave_sum_f(xj);
    float dot = wave_sum_f(x * xj);

    float m  = fmaxf(sqrtf(n2),  F_EPS_NORM);
    float mj = fmaxf(sqrtf(n2j), F_EPS_NORM);
    ebf[(size_t)row * DD + lane] = __float2bfloat16(x / m);

    __shared__ float spos[4];
    if (lane == 0) {
        float sq  = n2 / (m * m);
        float sqj = n2j / (mj * mj);
        float s   = sx / m;
        float sj  = sxj / mj;
        float g   = dot / (m * mj);
        u[row]  = sq + 2.0f * F_EPS_PD * s;
        vc[row] = sq - 2.0f * F_EPS_PD * s + (float)DD * F_EPS_PD * F_EPS_PD;
        float d2p = sq + sqj - 2.0f * g + 2.0f * F_EPS_PD * (s - sj)
                  + (float)DD * F_EPS_PD * F_EPS_PD;
        spos[w] = fmaxf(d2p, 0.0f);
    }
    __syncthreads();
    if (threadIdx.x == 0)
        posP[blockIdx.x] = spos[0] + spos[1] + spos[2] + spos[3];
}

// ---------------------------------------------------------------------------
// Kernel 2: persistent pairwise blocks over triangular 128x128 tile-pairs.
// Main path per t-iteration (512 pairs): 4 MFMA + max-tree screen + uniform
// branch. Exact d2/hinge math + u/vc/lab gathers only in the rare (~2%)
// screened path. Negative counting is done analytically via label histogram
// in reduce_kernel. Off-diagonal tiles weighted x2 (gram symmetric; the
// antisymmetric 2*eps*(s_i-s_j) term is ~0.1 total vs ~655 budget).
// ---------------------------------------------------------------------------
__global__ __launch_bounds__(256) void pair_kernel(
    const short* __restrict__ ebf, const float* __restrict__ u,
    const float* __restrict__ vc, const int* __restrict__ lab,
    float* __restrict__ negP) {
    int w    = threadIdx.x >> 6;
    int lane = threadIdx.x & 63;
    int lrow = lane & 15, lkh = lane >> 4;

    float hacc = 0.0f;

    for (int k = blockIdx.x; k < NTRI; k += NBLK) {
        // decode triangular index -> (ti, tj)
        int ti = (int)(128.5f - sqrtf(128.5f * 128.5f - 2.0f * (float)k));
        ti = ti < 0 ? 0 : (ti > TT - 1 ? TT - 1 : ti);
        while (tri_off(ti) > k) --ti;
        while (ti < TT - 1 && tri_off(ti + 1) <= k) ++ti;
        int tj = ti + (k - tri_off(ti));

        int bi = ti * 128 + w * 32;
        int bj = tj * 128;

        const short* ab = ebf + (size_t)(bi + lrow) * DD + lkh * 8;
        bf16x8 a00 = *(const bf16x8*)(ab);
        bf16x8 a01 = *(const bf16x8*)(ab + 32);
        bf16x8 a10 = *(const bf16x8*)(ab + 16 * DD);
        bf16x8 a11 = *(const bf16x8*)(ab + 16 * DD + 32);

        const short* bb = ebf + (size_t)(bj + lrow) * DD + lkh * 8;
        float hp = 0.0f;

        #pragma unroll
        for (int t = 0; t < 8; ++t) {
            bf16x8 b0 = *(const bf16x8*)(bb + t * 16 * DD);
            bf16x8 b1 = *(const bf16x8*)(bb + t * 16 * DD + 32);
            f32x4 c0 = {0.f, 0.f, 0.f, 0.f};
            c0 = __builtin_amdgcn_mfma_f32_16x16x32_bf16(a00, b0, c0, 0, 0, 0);
            c0 = __builtin_amdgcn_mfma_f32_16x16x32_bf16(a01, b1, c0, 0, 0, 0);
            f32x4 c1 = {0.f, 0.f, 0.f, 0.f};
            c1 = __builtin_amdgcn_mfma_f32_16x16x32_bf16(a10, b0, c1, 0, 0, 0);
            c1 = __builtin_amdgcn_mfma_f32_16x16x32_bf16(a11, b1, c1, 0, 0, 0);

            float m0 = fmaxf(fmaxf(c0[0], c0[1]), fmaxf(c0[2], c0[3]));
            float m1 = fmaxf(fmaxf(c1[0], c1[1]), fmaxf(c1[2], c1[3]));
            if (__any(fmaxf(m0, m1) > SCREEN_T)) {     // rare (~2% of groups)
                int j = bj + t * 16 + lrow;
                float vj = vc[j]; int lj = lab[j];
                #pragma unroll
                for (int r = 0; r < 4; ++r) {
                    int i0 = bi + lkh * 4 + r;
                    float d2a = fmaf(-2.0f, c0[r], u[i0] + vj);
                    float d2b = fmaf(-2.0f, c1[r], u[i0 + 16] + vj);
                    float da = sqrtf(fmaxf(d2a, 1e-12f));
                    float db = sqrtf(fmaxf(d2b, 1e-12f));
                    float ha = fmaxf(1.0f - da, 0.0f);
                    float hb = fmaxf(1.0f - db, 0.0f);
                    if (lab[i0]      != lj) hp = fmaf(ha, ha, hp);
                    if (lab[i0 + 16] != lj) hp = fmaf(hb, hb, hp);
                }
            }
        }
        hacc += (ti == tj) ? hp : hp + hp;
    }

    hacc = wave_sum_f(hacc);
    __shared__ float sneg[4];
    if (lane == 0) sneg[w] = hacc;
    __syncthreads();
    if (threadIdx.x == 0)
        negP[blockIdx.x] = sneg[0] + sneg[1] + sneg[2] + sneg[3];
}

// ---------------------------------------------------------------------------
// Kernel 3: final reduction + label histogram -> analytic negative count.
//   n_neg = N^2 - sum_c n_c^2 ;  n_comparisons = N + n_neg
// ---------------------------------------------------------------------------
__global__ __launch_bounds__(256) void reduce_kernel(
    const float* __restrict__ posP, const float* __restrict__ negP,
    const int* __restrict__ lab, float* __restrict__ out) {
    __shared__ unsigned int hist[1024];
    int t = threadIdx.x;
    for (int i = t; i < 1024; i += 256) hist[i] = 0u;
    __syncthreads();
    for (int i = t; i < NN; i += 256) {
        int l = lab[i];
        l = l < 0 ? 0 : (l > 1023 ? 1023 : l);
        atomicAdd(&hist[l], 1u);
    }
    __syncthreads();

    float ps = 0.f, ns = 0.f;
    unsigned int sqc = 0u;
    for (int i = t; i < NPOSB; i += 256) ps += posP[i];
    for (int i = t; i < NBLK; i += 256) ns += negP[i];
    for (int i = t; i < 1024; i += 256) { unsigned int h = hist[i]; sqc += h * h; }

    ps = wave_sum_f(ps);
    ns = wave_sum_f(ns);
    #pragma unroll
    for (int o = 32; o >= 1; o >>= 1) sqc += __shfl_xor(sqc, o);

    __shared__ float sp[4], sn[4];
    __shared__ unsigned int sc[4];
    int w = t >> 6, lane = t & 63;
    if (lane == 0) { sp[w] = ps; sn[w] = ns; sc[w] = sqc; }
    __syncthreads();
    if (t == 0) {
        float pos = sp[0] + sp[1] + sp[2] + sp[3];
        float neg = sn[0] + sn[1] + sn[2] + sn[3];
        unsigned long long s2 = (unsigned long long)sc[0] + sc[1] + sc[2] + sc[3];
        unsigned long long nneg = (unsigned long long)NN * NN - s2;
        float ncomp = (float)((unsigned long long)NN + nneg);
        out[0] = (pos + neg) / ncomp;
    }
}

// ---------------------------------------------------------------------------
// ws layout (bytes):
//   u    @ 0        : 65536
//   vc   @ 65536    : 65536
//   ebf  @ 131072   : 2097152
//   posP @ 2228224  : 16384   (NPOSB=4096 floats)
//   negP @ 2244608  : 8192    (NBLK=2048 floats)
//   total ~2.25 MB
// ---------------------------------------------------------------------------
extern "C" void kernel_launch(void* const* d_in, const int* in_sizes, int n_in,
                              void* d_out, int out_size, void* d_ws, size_t ws_size,
                              hipStream_t stream) {
    const float* emb = (const float*)d_in[0];
    const int* lab   = (const int*)d_in[1];
    const int* pidx  = (const int*)d_in[2];
    float* out = (float*)d_out;
    char* ws = (char*)d_ws;
    float*          u    = (float*)(ws);
    float*          vc   = (float*)(ws + 65536);
    __hip_bfloat16* ebf  = (__hip_bfloat16*)(ws + 131072);
    float*          posP = (float*)(ws + 2228224);
    float*          negP = (float*)(ws + 2244608);

    norm_kernel<<<NPOSB, 256, 0, stream>>>(emb, pidx, u, vc, ebf, posP);
    pair_kernel<<<NBLK, 256, 0, stream>>>((const short*)ebf, u, vc, lab, negP);
    reduce_kernel<<<1, 256, 0, stream>>>(posP, negP, lab, out);
}

// Round 4
// 57.427 us; speedup vs baseline: 2.0533x; 2.0533x over previous
//
#include <hip/hip_runtime.h>
#include <hip/hip_bf16.h>

#define NN 16384
#define DD 64
#define TT 128                 // 128-row tiles: NN/128
#define NTRI ((TT*(TT+1))/2)   // 8256 triangular tile-pairs
#define NBLK 1024              // 4 blocks/CU (32 KB LDS each) -> all resident
#define NPOSB (NN/4)           // norm blocks (4 rows each)
#define SCREEN_T 0.49f         // hinge>0 needs gram > ~0.5-3e-5; margin 1e-2

constexpr float F_EPS_PD   = 1e-6f;
constexpr float F_EPS_NORM = 1e-6f;

using bf16x8 = __attribute__((ext_vector_type(8))) short;
using f32x4  = __attribute__((ext_vector_type(4))) float;
typedef __attribute__((address_space(1))) const unsigned int gu32_t;
typedef __attribute__((address_space(3))) unsigned int       lu32_t;

__device__ __forceinline__ float wave_sum_f(float v) {
    #pragma unroll
    for (int o = 32; o >= 1; o >>= 1) v += __shfl_xor(v, o);
    return v;
}

__device__ __forceinline__ int tri_off(int t) { return t * TT - (t * (t - 1)) / 2; }

// ---------------------------------------------------------------------------
// Kernel 1: per-row normalize + bf16 copy + u/vc terms + exact fp32 pos loss.
//   u[i]  = sq_i + 2*eps*s_i
//   vc[j] = sq_j - 2*eps*s_j + D*eps*eps      (d2 = u_i + vc_j - 2*gram)
// ---------------------------------------------------------------------------
__global__ __launch_bounds__(256) void norm_kernel(
    const float* __restrict__ emb, const int* __restrict__ pidx,
    float* __restrict__ u, float* __restrict__ vc,
    __hip_bfloat16* __restrict__ ebf, float* __restrict__ posP) {
    int w    = threadIdx.x >> 6;
    int row  = blockIdx.x * 4 + w;
    int lane = threadIdx.x & 63;
    int j    = pidx[row];
    float x  = emb[(size_t)row * DD + lane];
    float xj = emb[(size_t)j   * DD + lane];

    float n2  = wave_sum_f(x * x);
    float sx  = wave_sum_f(x);
    float n2j = wave_sum_f(xj * xj);
    float sxj = wave_sum_f(xj);
    float dot = wave_sum_f(x * xj);

    float m  = fmaxf(sqrtf(n2),  F_EPS_NORM);
    float mj = fmaxf(sqrtf(n2j), F_EPS_NORM);
    ebf[(size_t)row * DD + lane] = __float2bfloat16(x / m);

    __shared__ float spos[4];
    if (lane == 0) {
        float sq  = n2 / (m * m);
        float sqj = n2j / (mj * mj);
        float s   = sx / m;
        float sj  = sxj / mj;
        float g   = dot / (m * mj);
        u[row]  = sq + 2.0f * F_EPS_PD * s;
        vc[row] = sq - 2.0f * F_EPS_PD * s + (float)DD * F_EPS_PD * F_EPS_PD;
        float d2p = sq + sqj - 2.0f * g + 2.0f * F_EPS_PD * (s - sj)
                  + (float)DD * F_EPS_PD * F_EPS_PD;
        spos[w] = fmaxf(d2p, 0.0f);
    }
    __syncthreads();
    if (threadIdx.x == 0)
        posP[blockIdx.x] = spos[0] + spos[1] + spos[2] + spos[3];
}

// ---------------------------------------------------------------------------
// Kernel 2: persistent blocks, contiguous tile-range per block, B staged in
// LDS via global_load_lds (2-phase double buffer), chunk-major LDS layout
// [8 chunks][128 rows][8 bf16] -> conflict-free ds_read_b128.
// A-frags live in registers, reloaded only when ti changes.
// Screen: hinge possible only if gram > ~0.5; exact d2/label math on the
// rare (~2%) screened path. Negative count done analytically in reduce.
// Off-diagonal tiles weighted x2 (antisym eps term ~0.1 vs ~655 budget).
// ---------------------------------------------------------------------------
__global__ __launch_bounds__(256, 4) void pair_kernel(
    const short* __restrict__ ebf, const float* __restrict__ u,
    const float* __restrict__ vc, const int* __restrict__ lab,
    float* __restrict__ negP) {
    __shared__ short lbs[2][8192];   // 2 x 16 KB: [chunk(8)][row(128)][8 bf16]
    int tid  = threadIdx.x;
    int w    = tid >> 6;
    int lane = tid & 63;
    int lrow = lane & 15, lkh = lane >> 4;

    int ks = (int)(((long long)blockIdx.x * NTRI) / NBLK);
    int ke = (int)(((long long)(blockIdx.x + 1) * NTRI) / NBLK);

    // decode ks -> (ti, tj)
    int ti = (int)(128.5f - sqrtf(128.5f * 128.5f - 2.0f * (float)ks));
    ti = ti < 0 ? 0 : (ti > TT - 1 ? TT - 1 : ti);
    while (tri_off(ti) > ks) --ti;
    while (ti < TT - 1 && tri_off(ti + 1) <= ks) ++ti;
    int tj = ti + (ks - tri_off(ti));

    int srr  = (w & 1) * 64 + lane;   // staging source row within tile
    int wsel = w >> 1;                // staging chunk parity

    bf16x8 a00, a01, a10, a11;
    float hacc = 0.0f;
    int cur = 0;

    // ---- stage tile tj into buf 0; load A(ti) ----
    {
        const short* bt = ebf + (size_t)tj * (128 * DD);
        #pragma unroll
        for (int q = 0; q < 4; ++q) {
            int chunk = 2 * q + wsel;
            __builtin_amdgcn_global_load_lds(
                (gu32_t*)(const void*)(bt + (size_t)srr * DD + chunk * 8),
                (lu32_t*)(void*)&lbs[0][q * 2048 + w * 512], 16, 0, 0);
        }
        const short* ab = ebf + (size_t)(ti * 128 + w * 32 + lrow) * DD + lkh * 8;
        a00 = *(const bf16x8*)(ab);
        a01 = *(const bf16x8*)(ab + 32);
        a10 = *(const bf16x8*)(ab + 16 * DD);
        a11 = *(const bf16x8*)(ab + 16 * DD + 32);
    }
    __syncthreads();

    for (int k = ks; k < ke; ++k) {
        int nti = ti, ntj = tj + 1;
        bool more = (k + 1 < ke);
        if (more) {
            if (ntj == TT) { nti = ti + 1; ntj = nti; }
            const short* bt = ebf + (size_t)ntj * (128 * DD);
            #pragma unroll
            for (int q = 0; q < 4; ++q) {
                int chunk = 2 * q + wsel;
                __builtin_amdgcn_global_load_lds(
                    (gu32_t*)(const void*)(bt + (size_t)srr * DD + chunk * 8),
                    (lu32_t*)(void*)&lbs[cur ^ 1][q * 2048 + w * 512], 16, 0, 0);
            }
        }

        // ---- compute tile (ti, tj) from lbs[cur] ----
        int bi = ti * 128 + w * 32;
        int bj = tj * 128;
        const short* lb = lbs[cur];
        float hp = 0.0f;
        #pragma unroll
        for (int t = 0; t < 8; ++t) {
            bf16x8 b0 = *(const bf16x8*)&lb[lkh * 1024 + (t * 16 + lrow) * 8];
            bf16x8 b1 = *(const bf16x8*)&lb[(lkh + 4) * 1024 + (t * 16 + lrow) * 8];
            f32x4 c0 = {0.f, 0.f, 0.f, 0.f};
            c0 = __builtin_amdgcn_mfma_f32_16x16x32_bf16(a00, b0, c0, 0, 0, 0);
            c0 = __builtin_amdgcn_mfma_f32_16x16x32_bf16(a01, b1, c0, 0, 0, 0);
            f32x4 c1 = {0.f, 0.f, 0.f, 0.f};
            c1 = __builtin_amdgcn_mfma_f32_16x16x32_bf16(a10, b0, c1, 0, 0, 0);
            c1 = __builtin_amdgcn_mfma_f32_16x16x32_bf16(a11, b1, c1, 0, 0, 0);

            float m0 = fmaxf(fmaxf(c0[0], c0[1]), fmaxf(c0[2], c0[3]));
            float m1 = fmaxf(fmaxf(c1[0], c1[1]), fmaxf(c1[2], c1[3]));
            if (__any(fmaxf(m0, m1) > SCREEN_T)) {     // rare (~2%)
                int j = bj + t * 16 + lrow;
                float vj = vc[j]; int lj = lab[j];
                #pragma unroll
                for (int r = 0; r < 4; ++r) {
                    int i0 = bi + lkh * 4 + r;
                    float d2a = fmaf(-2.0f, c0[r], u[i0] + vj);
                    float d2b = fmaf(-2.0f, c1[r], u[i0 + 16] + vj);
                    float da = sqrtf(fmaxf(d2a, 1e-12f));
                    float db = sqrtf(fmaxf(d2b, 1e-12f));
                    float ha = fmaxf(1.0f - da, 0.0f);
                    float hb = fmaxf(1.0f - db, 0.0f);
                    if (lab[i0]      != lj) hp = fmaf(ha, ha, hp);
                    if (lab[i0 + 16] != lj) hp = fmaf(hb, hb, hp);
                }
            }
        }
        hacc += (ti == tj) ? hp : hp + hp;

        __syncthreads();            // drains vmcnt: next buf staged + readers done
        cur ^= 1;
        if (more && nti != ti) {    // row band changed: reload A
            const short* ab = ebf + (size_t)(nti * 128 + w * 32 + lrow) * DD + lkh * 8;
            a00 = *(const bf16x8*)(ab);
            a01 = *(const bf16x8*)(ab + 32);
            a10 = *(const bf16x8*)(ab + 16 * DD);
            a11 = *(const bf16x8*)(ab + 16 * DD + 32);
        }
        ti = nti; tj = ntj;
    }

    hacc = wave_sum_f(hacc);
    float* sred = (float*)lbs;      // reuse LDS for final block reduce
    if (lane == 0) sred[w] = hacc;
    __syncthreads();
    if (tid == 0)
        negP[blockIdx.x] = sred[0] + sred[1] + sred[2] + sred[3];
}

// ---------------------------------------------------------------------------
// Kernel 3: final reduction + label histogram -> analytic negative count.
//   n_neg = N^2 - sum_c n_c^2 ;  n_comparisons = N + n_neg
// ---------------------------------------------------------------------------
__global__ __launch_bounds__(256) void reduce_kernel(
    const float* __restrict__ posP, const float* __restrict__ negP,
    const int* __restrict__ lab, float* __restrict__ out) {
    __shared__ unsigned int hist[1024];
    int t = threadIdx.x;
    for (int i = t; i < 1024; i += 256) hist[i] = 0u;
    __syncthreads();
    for (int i = t; i < NN; i += 256) {
        int l = lab[i];
        l = l < 0 ? 0 : (l > 1023 ? 1023 : l);
        atomicAdd(&hist[l], 1u);
    }
    __syncthreads();

    float ps = 0.f, ns = 0.f;
    unsigned int sqc = 0u;
    for (int i = t; i < NPOSB; i += 256) ps += posP[i];
    for (int i = t; i < NBLK; i += 256) ns += negP[i];
    for (int i = t; i < 1024; i += 256) { unsigned int h = hist[i]; sqc += h * h; }

    ps = wave_sum_f(ps);
    ns = wave_sum_f(ns);
    #pragma unroll
    for (int o = 32; o >= 1; o >>= 1) sqc += __shfl_xor(sqc, o);

    __shared__ float sp[4], sn[4];
    __shared__ unsigned int sc[4];
    int w = t >> 6, lane = t & 63;
    if (lane == 0) { sp[w] = ps; sn[w] = ns; sc[w] = sqc; }
    __syncthreads();
    if (t == 0) {
        float pos = sp[0] + sp[1] + sp[2] + sp[3];
        float neg = sn[0] + sn[1] + sn[2] + sn[3];
        unsigned long long s2 = (unsigned long long)sc[0] + sc[1] + sc[2] + sc[3];
        unsigned long long nneg = (unsigned long long)NN * NN - s2;
        float ncomp = (float)((unsigned long long)NN + nneg);
        out[0] = (pos + neg) / ncomp;
    }
}

// ---------------------------------------------------------------------------
// ws layout (bytes):
//   u    @ 0        : 65536
//   vc   @ 65536    : 65536
//   ebf  @ 131072   : 2097152
//   posP @ 2228224  : 16384   (NPOSB=4096 floats)
//   negP @ 2244608  : 4096    (NBLK=1024 floats)
//   total ~2.25 MB
// ---------------------------------------------------------------------------
extern "C" void kernel_launch(void* const* d_in, const int* in_sizes, int n_in,
                              void* d_out, int out_size, void* d_ws, size_t ws_size,
                              hipStream_t stream) {
    const float* emb = (const float*)d_in[0];
    const int* lab   = (const int*)d_in[1];
    const int* pidx  = (const int*)d_in[2];
    float* out = (float*)d_out;
    char* ws = (char*)d_ws;
    float*          u    = (float*)(ws);
    float*          vc   = (float*)(ws + 65536);
    __hip_bfloat16* ebf  = (__hip_bfloat16*)(ws + 131072);
    float*          posP = (float*)(ws + 2228224);
    float*          negP = (float*)(ws + 2244608);

    norm_kernel<<<NPOSB, 256, 0, stream>>>(emb, pidx, u, vc, ebf, posP);
    pair_kernel<<<NBLK, 256, 0, stream>>>((const short*)ebf, u, vc, lab, negP);
    reduce_kernel<<<1, 256, 0, stream>>>(posP, negP, lab, out);
}